// Round 19
// baseline (901.520 us; speedup 1.0000x reference)
//
#include <hip/hip_runtime.h>
#include <math.h>

#define DIM 66
#define NPATH 17
#define WNUM 648
#define NHID 32
#define HPAD 40   // Hlds halves per edge (80B stride, 16B-aligned b128)
#define WROWS 656 // 648 rounded to 16

typedef _Float16 f16x8 __attribute__((ext_vector_type(8)));
typedef float f32x4 __attribute__((ext_vector_type(4)));

// ---------------- CG computation (device, mirrors reference exactly) ----------------

__device__ double dfact(int n){ double f=1.0; for(int i=2;i<=n;i++) f*=(double)i; return f; }

__device__ double su2_cg(int j1,int j2,int j3,int m1,int m2,int m3){
  if(m1+m2!=m3) return 0.0;
  double pre = sqrt((double)(2*j3+1)*dfact(j3+j1-j2)*dfact(j3-j1+j2)*dfact(j1+j2-j3)/dfact(j1+j2+j3+1));
  pre *= sqrt(dfact(j3+m3)*dfact(j3-m3)*dfact(j1-m1)*dfact(j1+m1)*dfact(j2-m2)*dfact(j2+m2));
  double s=0.0;
  for(int k=0;k<=j1+j2-j3;k++){
    int a0=k, a1=j1+j2-j3-k, a2=j1-m1-k, a3=j2+m2-k, a4=j3-j2+m1+k, a5=j3-j1-m2+k;
    if(a0<0||a1<0||a2<0||a3<0||a4<0||a5<0) continue;
    double d = dfact(a0)*dfact(a1)*dfact(a2)*dfact(a3)*dfact(a4)*dfact(a5);
    s += ((k&1)? -1.0:1.0)/d;
  }
  return pre*s;
}

__device__ void u_real_entry(int l, int row, int col, double& re, double& im){
  re=0.0; im=0.0;
  const double sq = 0.7071067811865476;
  int m = row - l;
  if(m>0){
    if(col==l+m) re = ((m&1)? -sq : sq);
    else if(col==l-m) re = sq;
  } else if(m==0){
    if(col==l) re = 1.0;
  } else {
    int am = -m;
    if(col==l+m) im = sq;
    else if(col==l-m) im = ((am&1)? sq : -sq);
  }
}

__constant__ int c_l1[NPATH]   = {0,0,0,1,1,1,1,1,1,1,1,1,2,2,2,2,2};
__constant__ int c_l2[NPATH]   = {0,1,2,0,1,1,1,2,0,1,2,2,0,1,2,2,2};
__constant__ int c_l3[NPATH]   = {0,1,2,1,0,1,2,1,1,1,1,2,2,1,0,1,2};
__constant__ int c_cgoff[NPATH]= {0,1,10,35,44,53,80,125,170,179,206,251,326,351,396,421,496};

__global__ void cg_init_kernel(float* __restrict__ cg_out){
  int p = blockIdx.x;
  int l1=c_l1[p], l2=c_l2[p], l3=c_l3[p];
  int n1=2*l1+1, n2=2*l2+1, n3=2*l3+1;
  int ntot=n1*n2*n3;
  __shared__ double Cc[125];
  __shared__ double red[128];
  int t=threadIdx.x;
  if(t<ntot){
    int i=t/(n2*n3), j=(t/n3)%n2, k=t%n3;
    Cc[t] = su2_cg(l1,l2,l3,i-l1,j-l2,k-l3);
  }
  __syncthreads();
  double Tre=0.0, Tim=0.0;
  if(t<ntot){
    int a=t/(n2*n3), b=(t/n3)%n2, c=t%n3;
    for(int i=0;i<n1;i++)for(int j=0;j<n2;j++)for(int k=0;k<n3;k++){
      double cc=Cc[(i*n2+j)*n3+k];
      if(cc==0.0) continue;
      double u1r,u1i,u2r,u2i,u3r,u3i;
      u_real_entry(l1,a,i,u1r,u1i); u1i=-u1i;
      u_real_entry(l2,b,j,u2r,u2i); u2i=-u2i;
      u_real_entry(l3,c,k,u3r,u3i);
      double pr=u1r*u2r-u1i*u2i, pi=u1r*u2i+u1i*u2r;
      double qr=pr*u3r-pi*u3i,   qi=pr*u3i+pi*u3r;
      Tre+=qr*cc; Tim+=qi*cc;
    }
  }
  red[t]=fabs(Tre); __syncthreads();
  for(int s=64;s>0;s>>=1){ if(t<s) red[t]+=red[t+s]; __syncthreads(); }
  double sar=red[0]; __syncthreads();
  red[t]=fabs(Tim); __syncthreads();
  for(int s=64;s>0;s>>=1){ if(t<s) red[t]+=red[t+s]; __syncthreads(); }
  double sai=red[0]; __syncthreads();
  double chosen = (sar>=sai)? Tre : Tim;
  red[t]=chosen*chosen; __syncthreads();
  for(int s=64;s>0;s>>=1){ if(t<s) red[t]+=red[t+s]; __syncthreads(); }
  double nrm=sqrt(red[0]);
  if(t<ntot) cg_out[c_cgoff[p]+t] = (float)(chosen/nrm);
}

// ------- W -> f16: transpose + fold 1/sqrt(32), ORIGINAL path-order rows, pad to 656 -------

__global__ void wh_pack_kernel(const float* __restrict__ w2, _Float16* __restrict__ wh){
  int i=blockIdx.x*blockDim.x+threadIdx.x;
  if(i>=WROWS*NHID) return;
  int nr=i>>5, t=i&31;
  float val = (nr<WNUM) ? w2[t*WNUM+nr]*0.17677669529663687f : 0.f; // 1/sqrt(32)
  wh[i]=(_Float16)val;
}

// ---------------- per-node linears: h_in (lin_in) to ws, res to d_out ----------------

__global__ void linear_kernel(const float* __restrict__ h,
  const float* __restrict__ w0i, const float* __restrict__ w1oi, const float* __restrict__ w1ei,
  const float* __restrict__ w2i, const float* __restrict__ b0i,
  const float* __restrict__ w0r, const float* __restrict__ w1or_, const float* __restrict__ w1er,
  const float* __restrict__ w2r, const float* __restrict__ b0r,
  float* __restrict__ h_in, float* __restrict__ out, int total)
{
  int idx=blockIdx.x*blockDim.x+threadIdx.x;
  if(idx>=total) return;
  int d = idx % DIM;
  long bn = idx / DIM;
  const float* hr = h + bn*(long)DIM;
  float s1=0.f, s2=0.f, o1, o2;
  if(d<12){
    #pragma unroll
    for(int u=0;u<12;u++){ float xv=hr[u]; s1+=xv*w0i[u*12+d]; s2+=xv*w0r[u*12+d]; }
    const float r = 0.28867513459481287f;
    o1 = s1*r + b0i[d]; o2 = s2*r + b0r[d];
  } else if(d<24){
    int rel=d-12, v=rel/3, i=rel%3;
    #pragma unroll
    for(int u=0;u<4;u++){ float xv=hr[12+u*3+i]; s1+=xv*w1oi[u*4+v]; s2+=xv*w1or_[u*4+v]; }
    o1=s1*0.5f; o2=s2*0.5f;
  } else if(d<36){
    int rel=d-24, v=rel/3, i=rel%3;
    #pragma unroll
    for(int u=0;u<4;u++){ float xv=hr[24+u*3+i]; s1+=xv*w1ei[u*4+v]; s2+=xv*w1er[u*4+v]; }
    o1=s1*0.5f; o2=s2*0.5f;
  } else {
    int rel=d-36, v=rel/5, i=rel%5;
    #pragma unroll
    for(int u=0;u<6;u++){ float xv=hr[36+u*5+i]; s1+=xv*w2i[u*6+v]; s2+=xv*w2r[u*6+v]; }
    const float r=0.4082482904638631f;
    o1=s1*r; o2=s2*r;
  }
  h_in[idx]=o1; out[idx]=o2;
}

// ---------------- Kernel A: wv[648][BE] = W_f16 @ hid_f16 via MFMA, f16 to global ----------------
// block = 256 threads = 4 waves x 64 edges. Fragment mappings verified R16-R18.

__global__ __launch_bounds__(256) void wv_mfma_kernel(
  const float* __restrict__ e_attr, const float* __restrict__ rad_w1,
  const _Float16* __restrict__ wh, _Float16* __restrict__ wvg, int BE, int E)
{
  __shared__ _Float16 Hlds[64*HPAD];
  int tid=threadIdx.x, lane=tid&63, wave=tid>>6;
  int e0 = blockIdx.x*64;
  int el = e0 + lane;
  bool active = el < BE;
  float x=0.f,y=0.f,z=0.f;
  if(active){ const float* ea=e_attr+(long)el*3; x=ea[0]; y=ea[1]; z=ea[2]; }
  float rn=sqrtf(x*x+y*y+z*z)+1e-8f;
  #pragma unroll
  for(int j=0;j<8;j++){
    int t = wave*8 + j;
    float a = rn*rad_w1[t];
    Hlds[lane*HPAD + t] = (_Float16)(a/(1.f+expf(-a)));
  }
  __syncthreads();
  f16x8 bf0 = *(const f16x8*)(Hlds + ( 0 + (lane&15))*HPAD + (lane>>4)*8);
  f16x8 bf1 = *(const f16x8*)(Hlds + (16 + (lane&15))*HPAD + (lane>>4)*8);
  f16x8 bf2 = *(const f16x8*)(Hlds + (32 + (lane&15))*HPAD + (lane>>4)*8);
  f16x8 bf3 = *(const f16x8*)(Hlds + (48 + (lane&15))*HPAD + (lane>>4)*8);

  for(int rt=wave; rt<WROWS/16; rt+=4){
    f16x8 af = *(const f16x8*)(wh + (rt*16 + (lane&15))*NHID + (lane>>4)*8);
    f32x4 c0={0.f,0.f,0.f,0.f}, c1=c0, c2=c0, c3=c0;
    c0=__builtin_amdgcn_mfma_f32_16x16x32_f16(af,bf0,c0,0,0,0);
    c1=__builtin_amdgcn_mfma_f32_16x16x32_f16(af,bf1,c1,0,0,0);
    c2=__builtin_amdgcn_mfma_f32_16x16x32_f16(af,bf2,c2,0,0,0);
    c3=__builtin_amdgcn_mfma_f32_16x16x32_f16(af,bf3,c3,0,0,0);
    int rr = rt*16 + 4*(lane>>4);
    int ec = e0 + (lane&15);
    #pragma unroll
    for(int j=0;j<4;j++){
      int row = rr+j;
      if(row < WNUM){
        _Float16* wp = wvg + (size_t)row*BE + ec;
        if(ec    < BE) wp[ 0]=(_Float16)c0[j];
        if(ec+16 < BE) wp[16]=(_Float16)c1[j];
        if(ec+32 < BE) wp[32]=(_Float16)c2[j];
        if(ec+48 < BE) wp[48]=(_Float16)c3[j];
      }
    }
  }
}

// ---------------- Kernel B: TP + scatter; role = blockIdx.y handles v%4==ROLE ----------------
// 6256 waves (~6/SIMD). wv reads: e-major f16, fully coalesced. cg in LDS. hs via L1/L3.

template<int ROLE,int L1_,int L2_,int L3_,int MUL1,int MULO,int XOFF,int YOFF,int WOFF,int CGOFF,int OACC>
__device__ __forceinline__ void do_path_c(const float* __restrict__ hs, const float* Y,
  const _Float16* __restrict__ wvg, long el, size_t BEs, const float* __restrict__ cgl, float* acc)
{
  constexpr int N1=2*L1_+1, N2=2*L2_+1, N3=2*L3_+1;
  constexpr int NJ=(MULO+3)/4;
  float M[N1*N3];
  #pragma unroll
  for(int i=0;i<N1;i++){
    #pragma unroll
    for(int k=0;k<N3;k++){
      float s=0.f;
      #pragma unroll
      for(int j=0;j<N2;j++) s += Y[YOFF+j]*cgl[CGOFF+(i*N2+j)*N3+k];
      M[i*N3+k]=s;
    }
  }
  #pragma unroll
  for(int u=0;u<MUL1;u++){
    float zt[N3];
    #pragma unroll
    for(int k=0;k<N3;k++){
      float s=0.f;
      #pragma unroll
      for(int i=0;i<N1;i++) s += hs[XOFF+u*N1+i]*M[i*N3+k];
      zt[k]=s;
    }
    #pragma unroll
    for(int j=0;j<NJ;j++){
      int v = 4*j + ROLE;
      if(v < MULO){
        float w = (float)wvg[(size_t)(WOFF+u*MULO+v)*BEs + el];  // coalesced across lanes
        #pragma unroll
        for(int k=0;k<N3;k++) acc[OACC + j*N3 + k] += zt[k]*w;
      }
    }
  }
}

template<int ROLE>
__device__ __forceinline__ void edge_role_body(long el,
  const float* __restrict__ h_in, const int* __restrict__ e_src, const int* __restrict__ e_dst,
  const float* __restrict__ e_attr, const _Float16* __restrict__ wvg,
  const float* __restrict__ cgl, float* __restrict__ out, size_t BEs, int N, int E)
{
  int b = (int)(el / E);
  int src = e_src[el], dst = e_dst[el];
  const float* ea = e_attr + el*3;
  float x=ea[0], y=ea[1], z=ea[2];
  float rn = sqrtf(x*x+y*y+z*z) + 1e-8f;
  float xh=x/rn, yh=y/rn, zh=z/rn;
  float Y[9];
  const float s3=1.7320508075688772f, s5=2.23606797749979f, s15=3.872983346207417f;
  Y[0]=1.f; Y[1]=s3*yh; Y[2]=s3*zh; Y[3]=s3*xh;
  Y[4]=s15*xh*yh; Y[5]=s15*yh*zh; Y[6]=0.5f*s5*(3.f*zh*zh-1.f);
  Y[7]=s15*xh*zh; Y[8]=0.5f*s15*(xh*xh-yh*yh);
  const float* hs = h_in + ((long)b*N + src)*DIM;
  float acc[19];
  #pragma unroll
  for(int i=0;i<19;i++) acc[i]=0.f;

  // original R2-verified tables; OACC: g0=0,g1=3,g2=6,g3=9
  //           L1 L2 L3 M1 MO  XO YO WOFF CGOFF OACC
  do_path_c<ROLE,0,0,0,12,12,  0,0,   0,   0, 0>(hs,Y,wvg,el,BEs,cgl,acc);
  do_path_c<ROLE,0,1,1,12, 4,  0,1, 144,   1, 3>(hs,Y,wvg,el,BEs,cgl,acc);
  do_path_c<ROLE,0,2,2,12, 6,  0,4, 192,  10, 9>(hs,Y,wvg,el,BEs,cgl,acc);
  do_path_c<ROLE,1,0,1, 4, 4, 12,0, 264,  35, 3>(hs,Y,wvg,el,BEs,cgl,acc);
  do_path_c<ROLE,1,1,0, 4,12, 12,1, 280,  44, 0>(hs,Y,wvg,el,BEs,cgl,acc);
  do_path_c<ROLE,1,1,1, 4, 4, 12,1, 328,  53, 6>(hs,Y,wvg,el,BEs,cgl,acc);
  do_path_c<ROLE,1,1,2, 4, 6, 12,1, 344,  80, 9>(hs,Y,wvg,el,BEs,cgl,acc);
  do_path_c<ROLE,1,2,1, 4, 4, 12,4, 368, 125, 3>(hs,Y,wvg,el,BEs,cgl,acc);
  do_path_c<ROLE,1,0,1, 4, 4, 24,0, 384, 170, 6>(hs,Y,wvg,el,BEs,cgl,acc);
  do_path_c<ROLE,1,1,1, 4, 4, 24,1, 400, 179, 3>(hs,Y,wvg,el,BEs,cgl,acc);
  do_path_c<ROLE,1,2,1, 4, 4, 24,4, 416, 206, 6>(hs,Y,wvg,el,BEs,cgl,acc);
  do_path_c<ROLE,1,2,2, 4, 6, 24,4, 432, 251, 9>(hs,Y,wvg,el,BEs,cgl,acc);
  do_path_c<ROLE,2,0,2, 6, 6, 36,0, 456, 326, 9>(hs,Y,wvg,el,BEs,cgl,acc);
  do_path_c<ROLE,2,1,1, 6, 4, 36,1, 492, 351, 3>(hs,Y,wvg,el,BEs,cgl,acc);
  do_path_c<ROLE,2,2,0, 6,12, 36,4, 516, 396, 0>(hs,Y,wvg,el,BEs,cgl,acc);
  do_path_c<ROLE,2,2,1, 6, 4, 36,4, 588, 421, 6>(hs,Y,wvg,el,BEs,cgl,acc);
  do_path_c<ROLE,2,2,2, 6, 6, 36,4, 612, 496, 9>(hs,Y,wvg,el,BEs,cgl,acc);

  const float a0=0.21320071635561044f; // sqrt(1/22)
  const float a1=0.31622776601683794f; // sqrt(3/30)
  const float a2=0.4082482904638631f;  // sqrt(3/18)
  const float a3=0.3952847075210474f;  // sqrt(5/32)
  float* op = out + ((long)b*N + dst)*DIM;
  #pragma unroll
  for(int j=0;j<3;j++) unsafeAtomicAdd(&op[4*j+ROLE], acc[j]*a0);          // g0
  #pragma unroll
  for(int k=0;k<3;k++) unsafeAtomicAdd(&op[12+ROLE*3+k], acc[3+k]*a1);     // g1
  #pragma unroll
  for(int k=0;k<3;k++) unsafeAtomicAdd(&op[24+ROLE*3+k], acc[6+k]*a2);     // g2
  #pragma unroll
  for(int j=0;j<2;j++){                                                     // g3
    int v=4*j+ROLE;
    if(v<6){
      #pragma unroll
      for(int k=0;k<5;k++) unsafeAtomicAdd(&op[36+v*5+k], acc[9+5*j+k]*a3);
    }
  }
}

__global__ __launch_bounds__(256, 4) void tp_consume_kernel(
  const float* __restrict__ h_in, const int* __restrict__ e_src, const int* __restrict__ e_dst,
  const float* __restrict__ e_attr, const _Float16* __restrict__ wvg,
  const float* __restrict__ cg, float* __restrict__ out, int BE, int N, int E)
{
  __shared__ float cgl[640];
  for(int i=threadIdx.x;i<621;i+=256) cgl[i]=cg[i];
  __syncthreads();
  long el = (long)blockIdx.x*256 + threadIdx.x;
  if(el>=BE) return;
  size_t BEs = (size_t)BE;
  switch(blockIdx.y){
    case 0: edge_role_body<0>(el,h_in,e_src,e_dst,e_attr,wvg,cgl,out,BEs,N,E); break;
    case 1: edge_role_body<1>(el,h_in,e_src,e_dst,e_attr,wvg,cgl,out,BEs,N,E); break;
    case 2: edge_role_body<2>(el,h_in,e_src,e_dst,e_attr,wvg,cgl,out,BEs,N,E); break;
    default: edge_role_body<3>(el,h_in,e_src,e_dst,e_attr,wvg,cgl,out,BEs,N,E); break;
  }
}

// ---------------- norm_act (in place on d_out) ----------------

__global__ void norm_act_kernel(float* __restrict__ out, int total){
  int idx=blockIdx.x*blockDim.x+threadIdx.x;
  if(idx>=total) return;
  int c = idx % 26; long bn = idx / 26;
  int off, len;
  if(c<12){ off=c; len=1; }
  else if(c<16){ off=12+(c-12)*3; len=3; }
  else if(c<20){ off=24+(c-16)*3; len=3; }
  else { off=36+(c-20)*5; len=5; }
  float* p = out + bn*(long)DIM + off;
  float sum=0.f;
  for(int i=0;i<len;i++){ float v=p[i]; sum+=v*v; }
  float n = sqrtf(sum+1e-12f);
  float sc = 1.f/(1.f+expf(-n));  // silu(n)/n = sigmoid(n)
  for(int i=0;i<len;i++) p[i]*=sc;
}

// ---------------- launch ----------------

extern "C" void kernel_launch(void* const* d_in, const int* in_sizes, int n_in,
                              void* d_out, int out_size, void* d_ws, size_t ws_size,
                              hipStream_t stream)
{
  const float* h       = (const float*)d_in[0];
  const int*   e_src   = (const int*)  d_in[1];
  const int*   e_dst   = (const int*)  d_in[2];
  const float* e_attr  = (const float*)d_in[3];
  const float* lw0     = (const float*)d_in[4];
  const float* lw1o    = (const float*)d_in[5];
  const float* lw1e    = (const float*)d_in[6];
  const float* lw2     = (const float*)d_in[7];
  const float* lb0     = (const float*)d_in[8];
  const float* rw0     = (const float*)d_in[9];
  const float* rw1o    = (const float*)d_in[10];
  const float* rw1e    = (const float*)d_in[11];
  const float* rw2     = (const float*)d_in[12];
  const float* rb0     = (const float*)d_in[13];
  const float* rad_w1  = (const float*)d_in[14];
  const float* rad_w2  = (const float*)d_in[15];

  const int B  = 2;
  const int BE = in_sizes[1];        // B*E
  const int E  = BE / B;
  const int BN = in_sizes[0] / DIM;  // B*N
  const int N  = BN / B;

  float* ws   = (float*)d_ws;
  float* h_in = ws;                                   // BN*DIM floats
  float* cg   = ws + (size_t)BN*DIM;                  // 621 floats (pad to 640)
  _Float16* wh  = (_Float16*)(cg + 640);              // WROWS*NHID halves
  _Float16* wvg = wh + (size_t)WROWS*NHID;            // WNUM*BE halves (~130 MB)

  cg_init_kernel<<<NPATH, 128, 0, stream>>>(cg);
  int whn = WROWS*NHID;
  wh_pack_kernel<<<(whn+255)/256, 256, 0, stream>>>(rad_w2, wh);
  int totL = BN*DIM;
  linear_kernel<<<(totL+255)/256, 256, 0, stream>>>(h, lw0, lw1o, lw1e, lw2, lb0,
                                                    rw0, rw1o, rw1e, rw2, rb0,
                                                    h_in, (float*)d_out, totL);
  int ablk = (BE+63)/64;
  wv_mfma_kernel<<<ablk, 256, 0, stream>>>(e_attr, rad_w1, wh, wvg, BE, E);
  dim3 bgrid((BE+255)/256, 4);
  tp_consume_kernel<<<bgrid, 256, 0, stream>>>(h_in, e_src, e_dst, e_attr,
                                               wvg, cg, (float*)d_out, BE, N, E);
  int totN = BN*26;
  norm_act_kernel<<<(totN+255)/256, 256, 0, stream>>>((float*)d_out, totN);
}

// Round 20
// 568.592 us; speedup vs baseline: 1.5855x; 1.5855x over previous
//
#include <hip/hip_runtime.h>
#include <math.h>

#define DIM 66
#define NPATH 17
#define WNUM 648
#define NHID 32
#define HPAD 40   // Hlds halves per edge (80B stride, 16B-aligned b128)
#define WROWS 656 // 648 rounded to 16

typedef _Float16 f16x8 __attribute__((ext_vector_type(8)));
typedef float f32x4 __attribute__((ext_vector_type(4)));

// ---------------- CG computation (device, mirrors reference exactly) ----------------

__device__ double dfact(int n){ double f=1.0; for(int i=2;i<=n;i++) f*=(double)i; return f; }

__device__ double su2_cg(int j1,int j2,int j3,int m1,int m2,int m3){
  if(m1+m2!=m3) return 0.0;
  double pre = sqrt((double)(2*j3+1)*dfact(j3+j1-j2)*dfact(j3-j1+j2)*dfact(j1+j2-j3)/dfact(j1+j2+j3+1));
  pre *= sqrt(dfact(j3+m3)*dfact(j3-m3)*dfact(j1-m1)*dfact(j1+m1)*dfact(j2-m2)*dfact(j2+m2));
  double s=0.0;
  for(int k=0;k<=j1+j2-j3;k++){
    int a0=k, a1=j1+j2-j3-k, a2=j1-m1-k, a3=j2+m2-k, a4=j3-j2+m1+k, a5=j3-j1-m2+k;
    if(a0<0||a1<0||a2<0||a3<0||a4<0||a5<0) continue;
    double d = dfact(a0)*dfact(a1)*dfact(a2)*dfact(a3)*dfact(a4)*dfact(a5);
    s += ((k&1)? -1.0:1.0)/d;
  }
  return pre*s;
}

__device__ void u_real_entry(int l, int row, int col, double& re, double& im){
  re=0.0; im=0.0;
  const double sq = 0.7071067811865476;
  int m = row - l;
  if(m>0){
    if(col==l+m) re = ((m&1)? -sq : sq);
    else if(col==l-m) re = sq;
  } else if(m==0){
    if(col==l) re = 1.0;
  } else {
    int am = -m;
    if(col==l+m) im = sq;
    else if(col==l-m) im = ((am&1)? sq : -sq);
  }
}

__constant__ int c_l1[NPATH]   = {0,0,0,1,1,1,1,1,1,1,1,1,2,2,2,2,2};
__constant__ int c_l2[NPATH]   = {0,1,2,0,1,1,1,2,0,1,2,2,0,1,2,2,2};
__constant__ int c_l3[NPATH]   = {0,1,2,1,0,1,2,1,1,1,1,2,2,1,0,1,2};
__constant__ int c_cgoff[NPATH]= {0,1,10,35,44,53,80,125,170,179,206,251,326,351,396,421,496};

__global__ void cg_init_kernel(float* __restrict__ cg_out){
  int p = blockIdx.x;
  int l1=c_l1[p], l2=c_l2[p], l3=c_l3[p];
  int n1=2*l1+1, n2=2*l2+1, n3=2*l3+1;
  int ntot=n1*n2*n3;
  __shared__ double Cc[125];
  __shared__ double red[128];
  int t=threadIdx.x;
  if(t<ntot){
    int i=t/(n2*n3), j=(t/n3)%n2, k=t%n3;
    Cc[t] = su2_cg(l1,l2,l3,i-l1,j-l2,k-l3);
  }
  __syncthreads();
  double Tre=0.0, Tim=0.0;
  if(t<ntot){
    int a=t/(n2*n3), b=(t/n3)%n2, c=t%n3;
    for(int i=0;i<n1;i++)for(int j=0;j<n2;j++)for(int k=0;k<n3;k++){
      double cc=Cc[(i*n2+j)*n3+k];
      if(cc==0.0) continue;
      double u1r,u1i,u2r,u2i,u3r,u3i;
      u_real_entry(l1,a,i,u1r,u1i); u1i=-u1i;
      u_real_entry(l2,b,j,u2r,u2i); u2i=-u2i;
      u_real_entry(l3,c,k,u3r,u3i);
      double pr=u1r*u2r-u1i*u2i, pi=u1r*u2i+u1i*u2r;
      double qr=pr*u3r-pi*u3i,   qi=pr*u3i+pi*u3r;
      Tre+=qr*cc; Tim+=qi*cc;
    }
  }
  red[t]=fabs(Tre); __syncthreads();
  for(int s=64;s>0;s>>=1){ if(t<s) red[t]+=red[t+s]; __syncthreads(); }
  double sar=red[0]; __syncthreads();
  red[t]=fabs(Tim); __syncthreads();
  for(int s=64;s>0;s>>=1){ if(t<s) red[t]+=red[t+s]; __syncthreads(); }
  double sai=red[0]; __syncthreads();
  double chosen = (sar>=sai)? Tre : Tim;
  red[t]=chosen*chosen; __syncthreads();
  for(int s=64;s>0;s>>=1){ if(t<s) red[t]+=red[t+s]; __syncthreads(); }
  double nrm=sqrt(red[0]);
  if(t<ntot) cg_out[c_cgoff[p]+t] = (float)(chosen/nrm);
}

// ------- W -> f16: transpose + fold 1/sqrt(32), ORIGINAL path-order rows, pad to 656 -------

__global__ void wh_pack_kernel(const float* __restrict__ w2, _Float16* __restrict__ wh){
  int i=blockIdx.x*blockDim.x+threadIdx.x;
  if(i>=WROWS*NHID) return;
  int nr=i>>5, t=i&31;
  float val = (nr<WNUM) ? w2[t*WNUM+nr]*0.17677669529663687f : 0.f; // 1/sqrt(32)
  wh[i]=(_Float16)val;
}

// ---------------- per-node linears: h_in (lin_in) to ws, res to d_out ----------------

__global__ void linear_kernel(const float* __restrict__ h,
  const float* __restrict__ w0i, const float* __restrict__ w1oi, const float* __restrict__ w1ei,
  const float* __restrict__ w2i, const float* __restrict__ b0i,
  const float* __restrict__ w0r, const float* __restrict__ w1or_, const float* __restrict__ w1er,
  const float* __restrict__ w2r, const float* __restrict__ b0r,
  float* __restrict__ h_in, float* __restrict__ out, int total)
{
  int idx=blockIdx.x*blockDim.x+threadIdx.x;
  if(idx>=total) return;
  int d = idx % DIM;
  long bn = idx / DIM;
  const float* hr = h + bn*(long)DIM;
  float s1=0.f, s2=0.f, o1, o2;
  if(d<12){
    #pragma unroll
    for(int u=0;u<12;u++){ float xv=hr[u]; s1+=xv*w0i[u*12+d]; s2+=xv*w0r[u*12+d]; }
    const float r = 0.28867513459481287f;
    o1 = s1*r + b0i[d]; o2 = s2*r + b0r[d];
  } else if(d<24){
    int rel=d-12, v=rel/3, i=rel%3;
    #pragma unroll
    for(int u=0;u<4;u++){ float xv=hr[12+u*3+i]; s1+=xv*w1oi[u*4+v]; s2+=xv*w1or_[u*4+v]; }
    o1=s1*0.5f; o2=s2*0.5f;
  } else if(d<36){
    int rel=d-24, v=rel/3, i=rel%3;
    #pragma unroll
    for(int u=0;u<4;u++){ float xv=hr[24+u*3+i]; s1+=xv*w1ei[u*4+v]; s2+=xv*w1er[u*4+v]; }
    o1=s1*0.5f; o2=s2*0.5f;
  } else {
    int rel=d-36, v=rel/5, i=rel%5;
    #pragma unroll
    for(int u=0;u<6;u++){ float xv=hr[36+u*5+i]; s1+=xv*w2i[u*6+v]; s2+=xv*w2r[u*6+v]; }
    const float r=0.4082482904638631f;
    o1=s1*r; o2=s2*r;
  }
  h_in[idx]=o1; out[idx]=o2;
}

// ---------------- Kernel A: wv[648][BE] = W_f16 @ hid_f16 via MFMA, f16 to global ----------------
// (verified R19: correct numerics, absmax 0.125)

__global__ __launch_bounds__(256) void wv_mfma_kernel(
  const float* __restrict__ e_attr, const float* __restrict__ rad_w1,
  const _Float16* __restrict__ wh, _Float16* __restrict__ wvg, int BE, int E)
{
  __shared__ _Float16 Hlds[64*HPAD];
  int tid=threadIdx.x, lane=tid&63, wave=tid>>6;
  int e0 = blockIdx.x*64;
  int el = e0 + lane;
  bool active = el < BE;
  float x=0.f,y=0.f,z=0.f;
  if(active){ const float* ea=e_attr+(long)el*3; x=ea[0]; y=ea[1]; z=ea[2]; }
  float rn=sqrtf(x*x+y*y+z*z)+1e-8f;
  #pragma unroll
  for(int j=0;j<8;j++){
    int t = wave*8 + j;
    float a = rn*rad_w1[t];
    Hlds[lane*HPAD + t] = (_Float16)(a/(1.f+expf(-a)));
  }
  __syncthreads();
  f16x8 bf0 = *(const f16x8*)(Hlds + ( 0 + (lane&15))*HPAD + (lane>>4)*8);
  f16x8 bf1 = *(const f16x8*)(Hlds + (16 + (lane&15))*HPAD + (lane>>4)*8);
  f16x8 bf2 = *(const f16x8*)(Hlds + (32 + (lane&15))*HPAD + (lane>>4)*8);
  f16x8 bf3 = *(const f16x8*)(Hlds + (48 + (lane&15))*HPAD + (lane>>4)*8);

  for(int rt=wave; rt<WROWS/16; rt+=4){
    f16x8 af = *(const f16x8*)(wh + (rt*16 + (lane&15))*NHID + (lane>>4)*8);
    f32x4 c0={0.f,0.f,0.f,0.f}, c1=c0, c2=c0, c3=c0;
    c0=__builtin_amdgcn_mfma_f32_16x16x32_f16(af,bf0,c0,0,0,0);
    c1=__builtin_amdgcn_mfma_f32_16x16x32_f16(af,bf1,c1,0,0,0);
    c2=__builtin_amdgcn_mfma_f32_16x16x32_f16(af,bf2,c2,0,0,0);
    c3=__builtin_amdgcn_mfma_f32_16x16x32_f16(af,bf3,c3,0,0,0);
    int rr = rt*16 + 4*(lane>>4);
    int ec = e0 + (lane&15);
    #pragma unroll
    for(int j=0;j<4;j++){
      int row = rr+j;
      if(row < WNUM){
        _Float16* wp = wvg + (size_t)row*BE + ec;
        if(ec    < BE) wp[ 0]=(_Float16)c0[j];
        if(ec+16 < BE) wp[16]=(_Float16)c1[j];
        if(ec+32 < BE) wp[32]=(_Float16)c2[j];
        if(ec+48 < BE) wp[48]=(_Float16)c3[j];
      }
    }
  }
}

// ---------------- Kernel B: one thread per (edge, output channel) ----------------
// 6.6M threads = ~100 waves/SIMD: latency-proof. d = blockIdx.y (wave-uniform:
// cg reads broadcast, group branch uniform). wv reads coalesced (el-contiguous).
// Single-float accumulator -> ~40 VGPR, no spill possible.

template<int L1_,int L2_,int L3_,int MUL1,int MULO,int XOFF,int YOFF,int WOFF,int CGOFF>
__device__ __forceinline__ void do_path_d(const float* __restrict__ hs, const float* Y,
  const _Float16* __restrict__ wvg, long el, size_t BEs, const float* __restrict__ cgl,
  int v, int k, float& acc)
{
  constexpr int N1=2*L1_+1, N2=2*L2_+1, N3=2*L3_+1;
  float M[N1];
  #pragma unroll
  for(int i=0;i<N1;i++){
    float s=0.f;
    #pragma unroll
    for(int j=0;j<N2;j++) s += Y[YOFF+j]*cgl[CGOFF+(i*N2+j)*N3+k];
    M[i]=s;
  }
  #pragma unroll
  for(int u=0;u<MUL1;u++){
    float z=0.f;
    #pragma unroll
    for(int i=0;i<N1;i++) z += hs[XOFF+u*N1+i]*M[i];
    float w = (float)wvg[(size_t)(WOFF+u*MULO+v)*BEs + el];
    acc += z*w;
  }
}

__global__ __launch_bounds__(256) void tp_out_kernel(
  const float* __restrict__ h_in, const int* __restrict__ e_src, const int* __restrict__ e_dst,
  const float* __restrict__ e_attr, const _Float16* __restrict__ wvg,
  const float* __restrict__ cg, float* __restrict__ out, int BE, int N, int E)
{
  __shared__ float cgl[640];
  for(int i=threadIdx.x;i<621;i+=256) cgl[i]=cg[i];
  __syncthreads();
  long el = (long)blockIdx.x*256 + threadIdx.x;
  if(el>=BE) return;
  int d = blockIdx.y;                 // 0..65, block-uniform
  size_t BEs = (size_t)BE;
  int b = (int)(el / E);
  int src = e_src[el], dst = e_dst[el];
  const float* ea = e_attr + el*3;
  float x=ea[0], y=ea[1], z=ea[2];
  float rn = sqrtf(x*x+y*y+z*z) + 1e-8f;
  float xh=x/rn, yh=y/rn, zh=z/rn;
  float Y[9];
  const float s3=1.7320508075688772f, s5=2.23606797749979f, s15=3.872983346207417f;
  Y[0]=1.f; Y[1]=s3*yh; Y[2]=s3*zh; Y[3]=s3*xh;
  Y[4]=s15*xh*yh; Y[5]=s15*yh*zh; Y[6]=0.5f*s5*(3.f*zh*zh-1.f);
  Y[7]=s15*xh*zh; Y[8]=0.5f*s15*(xh*xh-yh*yh);
  const float* hs = h_in + ((long)b*N + src)*DIM;
  float acc=0.f;
  float alpha;

  if(d<12){                                   // group 0: v=d, k=0
    int v=d, k=0;
    //         L1 L2 L3 M1 MO  XO YO WOFF CGOFF
    do_path_d<0,0,0,12,12,  0,0,   0,   0>(hs,Y,wvg,el,BEs,cgl,v,k,acc);
    do_path_d<1,1,0, 4,12, 12,1, 280,  44>(hs,Y,wvg,el,BEs,cgl,v,k,acc);
    do_path_d<2,2,0, 6,12, 36,4, 516, 396>(hs,Y,wvg,el,BEs,cgl,v,k,acc);
    alpha=0.21320071635561044f;               // sqrt(1/22)
  } else if(d<24){                            // group 1: v=(d-12)/3, k=(d-12)%3
    int rel=d-12, v=rel/3, k=rel%3;
    do_path_d<0,1,1,12, 4,  0,1, 144,   1>(hs,Y,wvg,el,BEs,cgl,v,k,acc);
    do_path_d<1,0,1, 4, 4, 12,0, 264,  35>(hs,Y,wvg,el,BEs,cgl,v,k,acc);
    do_path_d<1,2,1, 4, 4, 12,4, 368, 125>(hs,Y,wvg,el,BEs,cgl,v,k,acc);
    do_path_d<1,1,1, 4, 4, 24,1, 400, 179>(hs,Y,wvg,el,BEs,cgl,v,k,acc);
    do_path_d<2,1,1, 6, 4, 36,1, 492, 351>(hs,Y,wvg,el,BEs,cgl,v,k,acc);
    alpha=0.31622776601683794f;               // sqrt(3/30)
  } else if(d<36){                            // group 2: v=(d-24)/3, k=(d-24)%3
    int rel=d-24, v=rel/3, k=rel%3;
    do_path_d<1,1,1, 4, 4, 12,1, 328,  53>(hs,Y,wvg,el,BEs,cgl,v,k,acc);
    do_path_d<1,0,1, 4, 4, 24,0, 384, 170>(hs,Y,wvg,el,BEs,cgl,v,k,acc);
    do_path_d<1,2,1, 4, 4, 24,4, 416, 206>(hs,Y,wvg,el,BEs,cgl,v,k,acc);
    do_path_d<2,2,1, 6, 4, 36,4, 588, 421>(hs,Y,wvg,el,BEs,cgl,v,k,acc);
    alpha=0.4082482904638631f;                // sqrt(3/18)
  } else {                                    // group 3: v=(d-36)/5, k=(d-36)%5
    int rel=d-36, v=rel/5, k=rel%5;
    do_path_d<0,2,2,12, 6,  0,4, 192,  10>(hs,Y,wvg,el,BEs,cgl,v,k,acc);
    do_path_d<1,1,2, 4, 6, 12,1, 344,  80>(hs,Y,wvg,el,BEs,cgl,v,k,acc);
    do_path_d<1,2,2, 4, 6, 24,4, 432, 251>(hs,Y,wvg,el,BEs,cgl,v,k,acc);
    do_path_d<2,0,2, 6, 6, 36,0, 456, 326>(hs,Y,wvg,el,BEs,cgl,v,k,acc);
    do_path_d<2,2,2, 6, 6, 36,4, 612, 496>(hs,Y,wvg,el,BEs,cgl,v,k,acc);
    alpha=0.3952847075210474f;                // sqrt(5/32)
  }

  unsafeAtomicAdd(&out[((long)b*N + dst)*DIM + d], acc*alpha);
}

// ---------------- norm_act (in place on d_out) ----------------

__global__ void norm_act_kernel(float* __restrict__ out, int total){
  int idx=blockIdx.x*blockDim.x+threadIdx.x;
  if(idx>=total) return;
  int c = idx % 26; long bn = idx / 26;
  int off, len;
  if(c<12){ off=c; len=1; }
  else if(c<16){ off=12+(c-12)*3; len=3; }
  else if(c<20){ off=24+(c-16)*3; len=3; }
  else { off=36+(c-20)*5; len=5; }
  float* p = out + bn*(long)DIM + off;
  float sum=0.f;
  for(int i=0;i<len;i++){ float v=p[i]; sum+=v*v; }
  float n = sqrtf(sum+1e-12f);
  float sc = 1.f/(1.f+expf(-n));  // silu(n)/n = sigmoid(n)
  for(int i=0;i<len;i++) p[i]*=sc;
}

// ---------------- launch ----------------

extern "C" void kernel_launch(void* const* d_in, const int* in_sizes, int n_in,
                              void* d_out, int out_size, void* d_ws, size_t ws_size,
                              hipStream_t stream)
{
  const float* h       = (const float*)d_in[0];
  const int*   e_src   = (const int*)  d_in[1];
  const int*   e_dst   = (const int*)  d_in[2];
  const float* e_attr  = (const float*)d_in[3];
  const float* lw0     = (const float*)d_in[4];
  const float* lw1o    = (const float*)d_in[5];
  const float* lw1e    = (const float*)d_in[6];
  const float* lw2     = (const float*)d_in[7];
  const float* lb0     = (const float*)d_in[8];
  const float* rw0     = (const float*)d_in[9];
  const float* rw1o    = (const float*)d_in[10];
  const float* rw1e    = (const float*)d_in[11];
  const float* rw2     = (const float*)d_in[12];
  const float* rb0     = (const float*)d_in[13];
  const float* rad_w1  = (const float*)d_in[14];
  const float* rad_w2  = (const float*)d_in[15];

  const int B  = 2;
  const int BE = in_sizes[1];        // B*E
  const int E  = BE / B;
  const int BN = in_sizes[0] / DIM;  // B*N
  const int N  = BN / B;

  float* ws   = (float*)d_ws;
  float* h_in = ws;                                   // BN*DIM floats
  float* cg   = ws + (size_t)BN*DIM;                  // 621 floats (pad to 640)
  _Float16* wh  = (_Float16*)(cg + 640);              // WROWS*NHID halves
  _Float16* wvg = wh + (size_t)WROWS*NHID;            // WNUM*BE halves (~130 MB)

  cg_init_kernel<<<NPATH, 128, 0, stream>>>(cg);
  int whn = WROWS*NHID;
  wh_pack_kernel<<<(whn+255)/256, 256, 0, stream>>>(rad_w2, wh);
  int totL = BN*DIM;
  linear_kernel<<<(totL+255)/256, 256, 0, stream>>>(h, lw0, lw1o, lw1e, lw2, lb0,
                                                    rw0, rw1o, rw1e, rw2, rb0,
                                                    h_in, (float*)d_out, totL);
  int ablk = (BE+63)/64;
  wv_mfma_kernel<<<ablk, 256, 0, stream>>>(e_attr, rad_w1, wh, wvg, BE, E);
  dim3 bgrid((BE+255)/256, DIM);
  tp_out_kernel<<<bgrid, 256, 0, stream>>>(h_in, e_src, e_dst, e_attr,
                                           wvg, cg, (float*)d_out, BE, N, E);
  int totN = BN*26;
  norm_act_kernel<<<(totN+255)/256, 256, 0, stream>>>((float*)d_out, totN);
}

// Round 21
// 475.561 us; speedup vs baseline: 1.8957x; 1.1956x over previous
//
#include <hip/hip_runtime.h>
#include <math.h>

#define DIM 66
#define NPATH 17
#define WNUM 648
#define NHID 32
#define HPAD 40   // Hlds halves per edge (80B stride, 16B-aligned b128)
#define WROWS 656 // 648 rounded to 16

typedef _Float16 f16x8 __attribute__((ext_vector_type(8)));
typedef float f32x4 __attribute__((ext_vector_type(4)));

// ---------------- CG computation (device, mirrors reference exactly) ----------------

__device__ double dfact(int n){ double f=1.0; for(int i=2;i<=n;i++) f*=(double)i; return f; }

__device__ double su2_cg(int j1,int j2,int j3,int m1,int m2,int m3){
  if(m1+m2!=m3) return 0.0;
  double pre = sqrt((double)(2*j3+1)*dfact(j3+j1-j2)*dfact(j3-j1+j2)*dfact(j1+j2-j3)/dfact(j1+j2+j3+1));
  pre *= sqrt(dfact(j3+m3)*dfact(j3-m3)*dfact(j1-m1)*dfact(j1+m1)*dfact(j2-m2)*dfact(j2+m2));
  double s=0.0;
  for(int k=0;k<=j1+j2-j3;k++){
    int a0=k, a1=j1+j2-j3-k, a2=j1-m1-k, a3=j2+m2-k, a4=j3-j2+m1+k, a5=j3-j1-m2+k;
    if(a0<0||a1<0||a2<0||a3<0||a4<0||a5<0) continue;
    double d = dfact(a0)*dfact(a1)*dfact(a2)*dfact(a3)*dfact(a4)*dfact(a5);
    s += ((k&1)? -1.0:1.0)/d;
  }
  return pre*s;
}

__device__ void u_real_entry(int l, int row, int col, double& re, double& im){
  re=0.0; im=0.0;
  const double sq = 0.7071067811865476;
  int m = row - l;
  if(m>0){
    if(col==l+m) re = ((m&1)? -sq : sq);
    else if(col==l-m) re = sq;
  } else if(m==0){
    if(col==l) re = 1.0;
  } else {
    int am = -m;
    if(col==l+m) im = sq;
    else if(col==l-m) im = ((am&1)? sq : -sq);
  }
}

__constant__ int c_l1[NPATH]   = {0,0,0,1,1,1,1,1,1,1,1,1,2,2,2,2,2};
__constant__ int c_l2[NPATH]   = {0,1,2,0,1,1,1,2,0,1,2,2,0,1,2,2,2};
__constant__ int c_l3[NPATH]   = {0,1,2,1,0,1,2,1,1,1,1,2,2,1,0,1,2};
__constant__ int c_cgoff[NPATH]= {0,1,10,35,44,53,80,125,170,179,206,251,326,351,396,421,496};

__global__ void cg_init_kernel(float* __restrict__ cg_out){
  int p = blockIdx.x;
  int l1=c_l1[p], l2=c_l2[p], l3=c_l3[p];
  int n1=2*l1+1, n2=2*l2+1, n3=2*l3+1;
  int ntot=n1*n2*n3;
  __shared__ double Cc[125];
  __shared__ double red[128];
  int t=threadIdx.x;
  if(t<ntot){
    int i=t/(n2*n3), j=(t/n3)%n2, k=t%n3;
    Cc[t] = su2_cg(l1,l2,l3,i-l1,j-l2,k-l3);
  }
  __syncthreads();
  double Tre=0.0, Tim=0.0;
  if(t<ntot){
    int a=t/(n2*n3), b=(t/n3)%n2, c=t%n3;
    for(int i=0;i<n1;i++)for(int j=0;j<n2;j++)for(int k=0;k<n3;k++){
      double cc=Cc[(i*n2+j)*n3+k];
      if(cc==0.0) continue;
      double u1r,u1i,u2r,u2i,u3r,u3i;
      u_real_entry(l1,a,i,u1r,u1i); u1i=-u1i;
      u_real_entry(l2,b,j,u2r,u2i); u2i=-u2i;
      u_real_entry(l3,c,k,u3r,u3i);
      double pr=u1r*u2r-u1i*u2i, pi=u1r*u2i+u1i*u2r;
      double qr=pr*u3r-pi*u3i,   qi=pr*u3i+pi*u3r;
      Tre+=qr*cc; Tim+=qi*cc;
    }
  }
  red[t]=fabs(Tre); __syncthreads();
  for(int s=64;s>0;s>>=1){ if(t<s) red[t]+=red[t+s]; __syncthreads(); }
  double sar=red[0]; __syncthreads();
  red[t]=fabs(Tim); __syncthreads();
  for(int s=64;s>0;s>>=1){ if(t<s) red[t]+=red[t+s]; __syncthreads(); }
  double sai=red[0]; __syncthreads();
  double chosen = (sar>=sai)? Tre : Tim;
  red[t]=chosen*chosen; __syncthreads();
  for(int s=64;s>0;s>>=1){ if(t<s) red[t]+=red[t+s]; __syncthreads(); }
  double nrm=sqrt(red[0]);
  if(t<ntot) cg_out[c_cgoff[p]+t] = (float)(chosen/nrm);
}

// ------- W -> f16: transpose + fold 1/sqrt(32), ORIGINAL path-order rows, pad to 656 -------

__global__ void wh_pack_kernel(const float* __restrict__ w2, _Float16* __restrict__ wh){
  int i=blockIdx.x*blockDim.x+threadIdx.x;
  if(i>=WROWS*NHID) return;
  int nr=i>>5, t=i&31;
  float val = (nr<WNUM) ? w2[t*WNUM+nr]*0.17677669529663687f : 0.f; // 1/sqrt(32)
  wh[i]=(_Float16)val;
}

// ---------------- per-node linears: h_in (lin_in) to ws, res to d_out ----------------

__global__ void linear_kernel(const float* __restrict__ h,
  const float* __restrict__ w0i, const float* __restrict__ w1oi, const float* __restrict__ w1ei,
  const float* __restrict__ w2i, const float* __restrict__ b0i,
  const float* __restrict__ w0r, const float* __restrict__ w1or_, const float* __restrict__ w1er,
  const float* __restrict__ w2r, const float* __restrict__ b0r,
  float* __restrict__ h_in, float* __restrict__ out, int total)
{
  int idx=blockIdx.x*blockDim.x+threadIdx.x;
  if(idx>=total) return;
  int d = idx % DIM;
  long bn = idx / DIM;
  const float* hr = h + bn*(long)DIM;
  float s1=0.f, s2=0.f, o1, o2;
  if(d<12){
    #pragma unroll
    for(int u=0;u<12;u++){ float xv=hr[u]; s1+=xv*w0i[u*12+d]; s2+=xv*w0r[u*12+d]; }
    const float r = 0.28867513459481287f;
    o1 = s1*r + b0i[d]; o2 = s2*r + b0r[d];
  } else if(d<24){
    int rel=d-12, v=rel/3, i=rel%3;
    #pragma unroll
    for(int u=0;u<4;u++){ float xv=hr[12+u*3+i]; s1+=xv*w1oi[u*4+v]; s2+=xv*w1or_[u*4+v]; }
    o1=s1*0.5f; o2=s2*0.5f;
  } else if(d<36){
    int rel=d-24, v=rel/3, i=rel%3;
    #pragma unroll
    for(int u=0;u<4;u++){ float xv=hr[24+u*3+i]; s1+=xv*w1ei[u*4+v]; s2+=xv*w1er[u*4+v]; }
    o1=s1*0.5f; o2=s2*0.5f;
  } else {
    int rel=d-36, v=rel/5, i=rel%5;
    #pragma unroll
    for(int u=0;u<6;u++){ float xv=hr[36+u*5+i]; s1+=xv*w2i[u*6+v]; s2+=xv*w2r[u*6+v]; }
    const float r=0.4082482904638631f;
    o1=s1*r; o2=s2*r;
  }
  h_in[idx]=o1; out[idx]=o2;
}

// ---------------- Kernel A: wv[648][BE] = W_f16 @ hid_f16 via MFMA (verified R19/R20) ----------------

__global__ __launch_bounds__(256) void wv_mfma_kernel(
  const float* __restrict__ e_attr, const float* __restrict__ rad_w1,
  const _Float16* __restrict__ wh, _Float16* __restrict__ wvg, int BE, int E)
{
  __shared__ _Float16 Hlds[64*HPAD];
  int tid=threadIdx.x, lane=tid&63, wave=tid>>6;
  int e0 = blockIdx.x*64;
  int el = e0 + lane;
  bool active = el < BE;
  float x=0.f,y=0.f,z=0.f;
  if(active){ const float* ea=e_attr+(long)el*3; x=ea[0]; y=ea[1]; z=ea[2]; }
  float rn=sqrtf(x*x+y*y+z*z)+1e-8f;
  #pragma unroll
  for(int j=0;j<8;j++){
    int t = wave*8 + j;
    float a = rn*rad_w1[t];
    Hlds[lane*HPAD + t] = (_Float16)(a/(1.f+expf(-a)));
  }
  __syncthreads();
  f16x8 bf0 = *(const f16x8*)(Hlds + ( 0 + (lane&15))*HPAD + (lane>>4)*8);
  f16x8 bf1 = *(const f16x8*)(Hlds + (16 + (lane&15))*HPAD + (lane>>4)*8);
  f16x8 bf2 = *(const f16x8*)(Hlds + (32 + (lane&15))*HPAD + (lane>>4)*8);
  f16x8 bf3 = *(const f16x8*)(Hlds + (48 + (lane&15))*HPAD + (lane>>4)*8);

  for(int rt=wave; rt<WROWS/16; rt+=4){
    f16x8 af = *(const f16x8*)(wh + (rt*16 + (lane&15))*NHID + (lane>>4)*8);
    f32x4 c0={0.f,0.f,0.f,0.f}, c1=c0, c2=c0, c3=c0;
    c0=__builtin_amdgcn_mfma_f32_16x16x32_f16(af,bf0,c0,0,0,0);
    c1=__builtin_amdgcn_mfma_f32_16x16x32_f16(af,bf1,c1,0,0,0);
    c2=__builtin_amdgcn_mfma_f32_16x16x32_f16(af,bf2,c2,0,0,0);
    c3=__builtin_amdgcn_mfma_f32_16x16x32_f16(af,bf3,c3,0,0,0);
    int rr = rt*16 + 4*(lane>>4);
    int ec = e0 + (lane&15);
    #pragma unroll
    for(int j=0;j<4;j++){
      int row = rr+j;
      if(row < WNUM){
        _Float16* wp = wvg + (size_t)row*BE + ec;
        if(ec    < BE) wp[ 0]=(_Float16)c0[j];
        if(ec+16 < BE) wp[16]=(_Float16)c1[j];
        if(ec+32 < BE) wp[32]=(_Float16)c2[j];
        if(ec+48 < BE) wp[48]=(_Float16)c3[j];
      }
    }
  }
}

// ---------------- Kernel B: one thread per (edge, v-unit) ----------------
// 26 v-units: g0 v0..11 | g1 v0..3 | g2 v0..3 | g3 v0..5. Each thread reads each
// wv value ONCE, accumulates acc[N3], fires N3 atomics. grid=(26, edge-blocks):
// x-major dispatch -> 26 same-edge blocks consecutive -> hs/wv L2-local.
// ~2.6M threads = 40 waves/SIMD; live state ~50 VGPR, no spill.

template<int L1_,int L2_,int L3_,int MUL1,int MULO,int XOFF,int YOFF,int WOFF,int CGOFF>
__device__ __forceinline__ void do_path_v(const float* __restrict__ hs, const float* Y,
  const _Float16* __restrict__ wvg, long el, size_t BEs, const float* __restrict__ cgl,
  int v, float* acc)
{
  constexpr int N1=2*L1_+1, N2=2*L2_+1, N3=2*L3_+1;
  float M[N1*N3];
  #pragma unroll
  for(int i=0;i<N1;i++){
    #pragma unroll
    for(int k=0;k<N3;k++){
      float s=0.f;
      #pragma unroll
      for(int j=0;j<N2;j++) s += Y[YOFF+j]*cgl[CGOFF+(i*N2+j)*N3+k];
      M[i*N3+k]=s;
    }
  }
  #pragma unroll
  for(int u=0;u<MUL1;u++){
    float w = (float)wvg[(size_t)(WOFF+u*MULO+v)*BEs + el];  // read ONCE per (u,v)
    #pragma unroll
    for(int k=0;k<N3;k++){
      float z=0.f;
      #pragma unroll
      for(int i=0;i<N1;i++) z += hs[XOFF+u*N1+i]*M[i*N3+k];
      acc[k] += z*w;
    }
  }
}

__global__ __launch_bounds__(256) void tp_out_kernel(
  const float* __restrict__ h_in, const int* __restrict__ e_src, const int* __restrict__ e_dst,
  const float* __restrict__ e_attr, const _Float16* __restrict__ wvg,
  const float* __restrict__ cg, float* __restrict__ out, int BE, int N, int E)
{
  __shared__ float cgl[640];
  for(int i=threadIdx.x;i<621;i+=256) cgl[i]=cg[i];
  __syncthreads();
  long el = (long)blockIdx.y*256 + threadIdx.x;
  if(el>=BE) return;
  int vu = blockIdx.x;                // 0..25, block-uniform
  size_t BEs = (size_t)BE;
  int b = (int)(el / E);
  int src = e_src[el], dst = e_dst[el];
  const float* ea = e_attr + el*3;
  float x=ea[0], y=ea[1], z=ea[2];
  float rn = sqrtf(x*x+y*y+z*z) + 1e-8f;
  float xh=x/rn, yh=y/rn, zh=z/rn;
  float Y[9];
  const float s3=1.7320508075688772f, s5=2.23606797749979f, s15=3.872983346207417f;
  Y[0]=1.f; Y[1]=s3*yh; Y[2]=s3*zh; Y[3]=s3*xh;
  Y[4]=s15*xh*yh; Y[5]=s15*yh*zh; Y[6]=0.5f*s5*(3.f*zh*zh-1.f);
  Y[7]=s15*xh*zh; Y[8]=0.5f*s15*(xh*xh-yh*yh);
  const float* hs = h_in + ((long)b*N + src)*DIM;
  float* op = out + ((long)b*N + dst)*DIM;
  float acc[5];
  #pragma unroll
  for(int i=0;i<5;i++) acc[i]=0.f;

  if(vu<12){                                  // group 0: v=vu, N3=1 -> d=v
    int v=vu;
    //         L1 L2 L3 M1 MO  XO YO WOFF CGOFF
    do_path_v<0,0,0,12,12,  0,0,   0,   0>(hs,Y,wvg,el,BEs,cgl,v,acc);
    do_path_v<1,1,0, 4,12, 12,1, 280,  44>(hs,Y,wvg,el,BEs,cgl,v,acc);
    do_path_v<2,2,0, 6,12, 36,4, 516, 396>(hs,Y,wvg,el,BEs,cgl,v,acc);
    unsafeAtomicAdd(&op[v], acc[0]*0.21320071635561044f);             // sqrt(1/22)
  } else if(vu<16){                           // group 1: v=vu-12, N3=3 -> d=12+v*3+k
    int v=vu-12;
    do_path_v<0,1,1,12, 4,  0,1, 144,   1>(hs,Y,wvg,el,BEs,cgl,v,acc);
    do_path_v<1,0,1, 4, 4, 12,0, 264,  35>(hs,Y,wvg,el,BEs,cgl,v,acc);
    do_path_v<1,2,1, 4, 4, 12,4, 368, 125>(hs,Y,wvg,el,BEs,cgl,v,acc);
    do_path_v<1,1,1, 4, 4, 24,1, 400, 179>(hs,Y,wvg,el,BEs,cgl,v,acc);
    do_path_v<2,1,1, 6, 4, 36,1, 492, 351>(hs,Y,wvg,el,BEs,cgl,v,acc);
    #pragma unroll
    for(int k=0;k<3;k++) unsafeAtomicAdd(&op[12+v*3+k], acc[k]*0.31622776601683794f); // sqrt(3/30)
  } else if(vu<20){                           // group 2: v=vu-16, N3=3 -> d=24+v*3+k
    int v=vu-16;
    do_path_v<1,1,1, 4, 4, 12,1, 328,  53>(hs,Y,wvg,el,BEs,cgl,v,acc);
    do_path_v<1,0,1, 4, 4, 24,0, 384, 170>(hs,Y,wvg,el,BEs,cgl,v,acc);
    do_path_v<1,2,1, 4, 4, 24,4, 416, 206>(hs,Y,wvg,el,BEs,cgl,v,acc);
    do_path_v<2,2,1, 6, 4, 36,4, 588, 421>(hs,Y,wvg,el,BEs,cgl,v,acc);
    #pragma unroll
    for(int k=0;k<3;k++) unsafeAtomicAdd(&op[24+v*3+k], acc[k]*0.4082482904638631f);  // sqrt(3/18)
  } else {                                    // group 3: v=vu-20, N3=5 -> d=36+v*5+k
    int v=vu-20;
    do_path_v<0,2,2,12, 6,  0,4, 192,  10>(hs,Y,wvg,el,BEs,cgl,v,acc);
    do_path_v<1,1,2, 4, 6, 12,1, 344,  80>(hs,Y,wvg,el,BEs,cgl,v,acc);
    do_path_v<1,2,2, 4, 6, 24,4, 432, 251>(hs,Y,wvg,el,BEs,cgl,v,acc);
    do_path_v<2,0,2, 6, 6, 36,0, 456, 326>(hs,Y,wvg,el,BEs,cgl,v,acc);
    do_path_v<2,2,2, 6, 6, 36,4, 612, 496>(hs,Y,wvg,el,BEs,cgl,v,acc);
    #pragma unroll
    for(int k=0;k<5;k++) unsafeAtomicAdd(&op[36+v*5+k], acc[k]*0.3952847075210474f);  // sqrt(5/32)
  }
}

// ---------------- norm_act (in place on d_out) ----------------

__global__ void norm_act_kernel(float* __restrict__ out, int total){
  int idx=blockIdx.x*blockDim.x+threadIdx.x;
  if(idx>=total) return;
  int c = idx % 26; long bn = idx / 26;
  int off, len;
  if(c<12){ off=c; len=1; }
  else if(c<16){ off=12+(c-12)*3; len=3; }
  else if(c<20){ off=24+(c-16)*3; len=3; }
  else { off=36+(c-20)*5; len=5; }
  float* p = out + bn*(long)DIM + off;
  float sum=0.f;
  for(int i=0;i<len;i++){ float v=p[i]; sum+=v*v; }
  float n = sqrtf(sum+1e-12f);
  float sc = 1.f/(1.f+expf(-n));  // silu(n)/n = sigmoid(n)
  for(int i=0;i<len;i++) p[i]*=sc;
}

// ---------------- launch ----------------

extern "C" void kernel_launch(void* const* d_in, const int* in_sizes, int n_in,
                              void* d_out, int out_size, void* d_ws, size_t ws_size,
                              hipStream_t stream)
{
  const float* h       = (const float*)d_in[0];
  const int*   e_src   = (const int*)  d_in[1];
  const int*   e_dst   = (const int*)  d_in[2];
  const float* e_attr  = (const float*)d_in[3];
  const float* lw0     = (const float*)d_in[4];
  const float* lw1o    = (const float*)d_in[5];
  const float* lw1e    = (const float*)d_in[6];
  const float* lw2     = (const float*)d_in[7];
  const float* lb0     = (const float*)d_in[8];
  const float* rw0     = (const float*)d_in[9];
  const float* rw1o    = (const float*)d_in[10];
  const float* rw1e    = (const float*)d_in[11];
  const float* rw2     = (const float*)d_in[12];
  const float* rb0     = (const float*)d_in[13];
  const float* rad_w1  = (const float*)d_in[14];
  const float* rad_w2  = (const float*)d_in[15];

  const int B  = 2;
  const int BE = in_sizes[1];        // B*E
  const int E  = BE / B;
  const int BN = in_sizes[0] / DIM;  // B*N
  const int N  = BN / B;

  float* ws   = (float*)d_ws;
  float* h_in = ws;                                   // BN*DIM floats
  float* cg   = ws + (size_t)BN*DIM;                  // 621 floats (pad to 640)
  _Float16* wh  = (_Float16*)(cg + 640);              // WROWS*NHID halves
  _Float16* wvg = wh + (size_t)WROWS*NHID;            // WNUM*BE halves (~130 MB)

  cg_init_kernel<<<NPATH, 128, 0, stream>>>(cg);
  int whn = WROWS*NHID;
  wh_pack_kernel<<<(whn+255)/256, 256, 0, stream>>>(rad_w2, wh);
  int totL = BN*DIM;
  linear_kernel<<<(totL+255)/256, 256, 0, stream>>>(h, lw0, lw1o, lw1e, lw2, lb0,
                                                    rw0, rw1o, rw1e, rw2, rb0,
                                                    h_in, (float*)d_out, totL);
  int ablk = (BE+63)/64;
  wv_mfma_kernel<<<ablk, 256, 0, stream>>>(e_attr, rad_w1, wh, wvg, BE, E);
  dim3 bgrid(26, (BE+255)/256);
  tp_out_kernel<<<bgrid, 256, 0, stream>>>(h_in, e_src, e_dst, e_attr,
                                           wvg, cg, (float*)d_out, BE, N, E);
  int totN = BN*26;
  norm_act_kernel<<<(totN+255)/256, 256, 0, stream>>>((float*)d_out, totN);
}